// Round 4
// baseline (639.727 us; speedup 1.0000x reference)
//
#include <hip/hip_runtime.h>
#include <cstdint>
#include <cstddef>

#define N_NODES 10000
#define M_PAD   10112            // 79 * 128
#define N_EDGES 160000
#define ETOT    (N_EDGES + N_NODES)   // with self-loops
#define F_INDIM 300
#define K1PAD   320              // F_INDIM padded to mult of 32
#define HEADS   4
#define DH      256
#define C1      (HEADS * DH)     // 1024
#define NCLS    6
#define BN_EPS  1e-5f

typedef _Float16 half8 __attribute__((ext_vector_type(8)));
typedef _Float16 half4 __attribute__((ext_vector_type(4)));
typedef float f32x4 __attribute__((ext_vector_type(4)));

__device__ __forceinline__ void gld_lds16(const void* g, void* s) {
  __builtin_amdgcn_global_load_lds(
      (const __attribute__((address_space(1))) void*)g,
      (__attribute__((address_space(3))) void*)s, 16, 0, 0);
}

// ---------------------------------------------------------------------------
// fp16 MFMA GEMM: C[M,Nn] = A[M,K]fp16 @ B[Nn,K]fp16^T  (NT)
// 128x128 tile, BK=32, 256 threads = 4 waves (2x2), 4x4 16x16x32 frags/wave.
// LDS linear [128][32] halves: frag ds_read_b128 is conflict-free (64B rows).
// OUT16=1 -> fp16 output, else fp32.
// ---------------------------------------------------------------------------
template <int OUT16>
__global__ __launch_bounds__(256) void k_mfma_gemm(
    const _Float16* __restrict__ A, const _Float16* __restrict__ B,
    float* __restrict__ Cf, _Float16* __restrict__ Ch,
    int M, int Nn, int K) {
  __shared__ __align__(16) _Float16 sA[128 * 32];
  __shared__ __align__(16) _Float16 sB[128 * 32];
  const int tid = threadIdx.x;
  const int lane = tid & 63, w = tid >> 6;
  const int wm = w >> 1, wn = w & 1;
  const int row0 = blockIdx.y * 128, col0 = blockIdx.x * 128;

  const int r_loc = lane >> 2;       // 0..15
  const int j8 = (lane & 3) * 8;     // half offset within BK=32
  const _Float16* gA = A + (size_t)(row0 + w * 32 + r_loc) * K + j8;
  const _Float16* gB = B + (size_t)(col0 + w * 32 + r_loc) * K + j8;
  _Float16* sAw = sA + (w * 32) * 32;
  _Float16* sBw = sB + (w * 32) * 32;

  const int fr = lane & 15, kb = lane >> 4;
  const _Float16* pA = sA + ((size_t)(wm * 64 + fr) * 32 + kb * 8);
  const _Float16* pB = sB + ((size_t)(wn * 64 + fr) * 32 + kb * 8);

  f32x4 acc[4][4] = {};
  const int KT = K / 32;

  {
    gld_lds16(gA, sAw);
    gld_lds16(gA + (size_t)16 * K, sAw + 16 * 32);
    gld_lds16(gB, sBw);
    gld_lds16(gB + (size_t)16 * K, sBw + 16 * 32);
  }
  for (int kt = 0; kt < KT; ++kt) {
    __syncthreads();
    half8 af[4], bf[4];
#pragma unroll
    for (int i = 0; i < 4; ++i) af[i] = *(const half8*)(pA + i * 16 * 32);
#pragma unroll
    for (int j = 0; j < 4; ++j) bf[j] = *(const half8*)(pB + j * 16 * 32);
    __syncthreads();
    if (kt + 1 < KT) {
      const _Float16* ga = gA + (size_t)(kt + 1) * 32;
      const _Float16* gb = gB + (size_t)(kt + 1) * 32;
      gld_lds16(ga, sAw);
      gld_lds16(ga + (size_t)16 * K, sAw + 16 * 32);
      gld_lds16(gb, sBw);
      gld_lds16(gb + (size_t)16 * K, sBw + 16 * 32);
    }
#pragma unroll
    for (int i = 0; i < 4; ++i)
#pragma unroll
      for (int j = 0; j < 4; ++j)
        acc[i][j] =
            __builtin_amdgcn_mfma_f32_16x16x32_f16(af[i], bf[j], acc[i][j], 0, 0, 0);
  }

  // C/D layout: col = lane&15, row = (lane>>4)*4 + reg
  const int orow = row0 + wm * 64 + kb * 4;
  const int ocol = col0 + wn * 64 + fr;
#pragma unroll
  for (int i = 0; i < 4; ++i) {
#pragma unroll
    for (int r = 0; r < 4; ++r) {
      const int rr = orow + i * 16 + r;
      if (rr >= M) continue;
#pragma unroll
      for (int j = 0; j < 4; ++j) {
        if (OUT16) Ch[(size_t)rr * Nn + ocol + j * 16] = (_Float16)acc[i][j][r];
        else       Cf[(size_t)rr * Nn + ocol + j * 16] = acc[i][j][r];
      }
    }
  }
}

// ---------------------------------------------------------------------------
// fp32 -> fp16 conversion with K padding (zeros for k >= K)
// ---------------------------------------------------------------------------
__global__ __launch_bounds__(256) void k_cvt(const float* __restrict__ in,
                                             _Float16* __restrict__ out,
                                             int M, int K, int Kpad) {
  const int idx = blockIdx.x * 256 + threadIdx.x;
  const int kp2 = Kpad >> 1;
  if (idx >= M * kp2) return;
  const int r = idx / kp2, c2 = (idx % kp2) * 2;
  const float vx = (c2 < K) ? in[(size_t)r * K + c2] : 0.f;
  const float vy = (c2 + 1 < K) ? in[(size_t)r * K + c2 + 1] : 0.f;
  out[(size_t)r * Kpad + c2] = (_Float16)vx;
  out[(size_t)r * Kpad + c2 + 1] = (_Float16)vy;
}

// ---------------------------------------------------------------------------
// Generic fp32 GEMM (kept for the small MLP head)
// ---------------------------------------------------------------------------
template <int ACT> // 0 = none, 1 = relu
__global__ __launch_bounds__(256) void k_gemm(
    const float* __restrict__ A, const float* __restrict__ W,
    const float* __restrict__ bias, float* __restrict__ C,
    int M, int Nn, int K) {
  __shared__ float As[8][132];
  __shared__ float Bs[8][132];
  const int tid = threadIdx.x;
  const int tx = tid & 15, ty = tid >> 4;
  const int row0 = blockIdx.y * 128, col0 = blockIdx.x * 128;
  const int lr = tid >> 1;
  const int lc = (tid & 1) * 4;
  float acc[8][8] = {};
  for (int k0 = 0; k0 < K; k0 += 8) {
#pragma unroll
    for (int i = 0; i < 4; i++) {
      const int gc = k0 + lc + i;
      const int ar = row0 + lr;
      As[lc + i][lr] = (ar < M && gc < K) ? A[(size_t)ar * K + gc] : 0.f;
      const int wr = col0 + lr;
      Bs[lc + i][lr] = (wr < Nn && gc < K) ? W[(size_t)wr * K + gc] : 0.f;
    }
    __syncthreads();
#pragma unroll
    for (int kk = 0; kk < 8; kk++) {
      float a[8], b[8];
#pragma unroll
      for (int i = 0; i < 8; i++) a[i] = As[kk][ty * 8 + i];
#pragma unroll
      for (int j = 0; j < 8; j++) b[j] = Bs[kk][tx * 8 + j];
#pragma unroll
      for (int i = 0; i < 8; i++)
#pragma unroll
        for (int j = 0; j < 8; j++) acc[i][j] += a[i] * b[j];
    }
    __syncthreads();
  }
#pragma unroll
  for (int i = 0; i < 8; i++) {
    const int r = row0 + ty * 8 + i;
    if (r >= M) continue;
#pragma unroll
    for (int j = 0; j < 8; j++) {
      const int c = col0 + tx * 8 + j;
      if (c >= Nn) continue;
      float v = acc[i][j];
      if (bias) v += bias[c];
      if (ACT == 1) v = v > 0.f ? v : 0.f;
      C[(size_t)r * Nn + c] = v;
    }
  }
}

// ---------------------------------------------------------------------------
// alpha_s[n,h] = <h[n,h,:], a_src[h,:]> from fp16 h. Block = HH*64.
// ---------------------------------------------------------------------------
template <int HH>
__global__ __launch_bounds__(HH * 64) void k_alpha(
    const _Float16* __restrict__ h, const float* __restrict__ a_src,
    const float* __restrict__ a_dst, float* __restrict__ as_,
    float* __restrict__ ad_) {
  const int n = blockIdx.x;
  const int tid = threadIdx.x;
  const int head = tid >> 6;
  const int lane = tid & 63;
  const half4 hv = *(const half4*)(h + (size_t)n * HH * DH + head * DH + lane * 4);
  const float4 sv = *(reinterpret_cast<const float4*>(a_src + head * DH) + lane);
  const float4 dv = *(reinterpret_cast<const float4*>(a_dst + head * DH) + lane);
  const float h0 = (float)hv[0], h1 = (float)hv[1], h2 = (float)hv[2],
              h3 = (float)hv[3];
  float s1 = h0 * sv.x + h1 * sv.y + h2 * sv.z + h3 * sv.w;
  float s2 = h0 * dv.x + h1 * dv.y + h2 * dv.z + h3 * dv.w;
#pragma unroll
  for (int off = 32; off > 0; off >>= 1) {
    s1 += __shfl_down(s1, off);
    s2 += __shfl_down(s2, off);
  }
  if (lane == 0) {
    as_[n * HH + head] = s1;
    ad_[n * HH + head] = s2;
  }
}

// ---------------------------------------------------------------------------
// Per edge: all heads. w = exp(leaky_relu(as[src]+ad[dst])); write into CSR
// slot order (einv) so aggregation reads weights contiguously.
// ---------------------------------------------------------------------------
template <int HH>
__global__ __launch_bounds__(256) void k_edge(
    const int* __restrict__ ei, const int* __restrict__ einv,
    float* __restrict__ ewc, float* __restrict__ den,
    const float* __restrict__ as_, const float* __restrict__ ad_) {
  const int e = blockIdx.x * 256 + threadIdx.x;
  if (e >= ETOT) return;
  int s, t;
  if (e < N_EDGES) { s = ei[e]; t = ei[N_EDGES + e]; }
  else             { s = t = e - N_EDGES; }
  const int pos = einv[e];
#pragma unroll
  for (int hh = 0; hh < HH; ++hh) {
    float x = as_[s * HH + hh] + ad_[t * HH + hh];
    x = x > 0.f ? x : 0.2f * x;
    const float w = expf(x);
    ewc[(size_t)pos * HH + hh] = w;
    atomicAdd(&den[t * HH + hh], w);
  }
}

// ---------------------------------------------------------------------------
// CSR build
// ---------------------------------------------------------------------------
__global__ __launch_bounds__(256) void k_count(const int* __restrict__ ei,
                                               int* __restrict__ cnt) {
  const int e = blockIdx.x * 256 + threadIdx.x;
  if (e >= ETOT) return;
  const int t = (e < N_EDGES) ? ei[N_EDGES + e] : (e - N_EDGES);
  atomicAdd(&cnt[t], 1);
}

__global__ __launch_bounds__(256) void k_scan(const int* __restrict__ cnt,
                                              int* __restrict__ rowptr) {
  __shared__ int part[256];
  const int tid = threadIdx.x;
  const int chunk = (N_NODES + 255) / 256;  // 40
  const int b = tid * chunk;
  int sum = 0;
  for (int i = 0; i < chunk; i++) {
    const int idx = b + i;
    if (idx < N_NODES) sum += cnt[idx];
  }
  part[tid] = sum;
  __syncthreads();
  for (int off = 1; off < 256; off <<= 1) {
    int t2 = (tid >= off) ? part[tid - off] : 0;
    __syncthreads();
    part[tid] += t2;
    __syncthreads();
  }
  int run = part[tid] - sum;
  for (int i = 0; i < chunk; i++) {
    const int idx = b + i;
    if (idx < N_NODES) {
      rowptr[idx] = run;
      run += cnt[idx];
    }
  }
  if (tid == 255) rowptr[N_NODES] = part[255];
}

__global__ __launch_bounds__(256) void k_fill(
    const int* __restrict__ ei, const int* __restrict__ rowptr,
    int* __restrict__ fill, int* __restrict__ csr_src,
    int* __restrict__ einv) {
  const int e = blockIdx.x * 256 + threadIdx.x;
  if (e >= ETOT) return;
  int s, t;
  if (e < N_EDGES) { s = ei[e]; t = ei[N_EDGES + e]; }
  else             { s = t = e - N_EDGES; }
  const int pos = rowptr[t] + atomicAdd(&fill[t], 1);
  csr_src[pos] = s;
  einv[e] = pos;
}

// ---------------------------------------------------------------------------
// Aggregation from fp16 h: out[n] = epilogue( sum alpha_e * h[src_e] )
// ewc is CSR-slot-ordered -> contiguous weight reads.
// Writes fp16 (outh) or fp32 (outf).
// ---------------------------------------------------------------------------
template <int HH, bool DO_BN>
__global__ __launch_bounds__(HH * 64) void k_agg(
    const _Float16* __restrict__ h, const int* __restrict__ rowptr,
    const int* __restrict__ csr_src, const float* __restrict__ ewc,
    const float* __restrict__ den, const float* __restrict__ bias,
    const float* __restrict__ gg, const float* __restrict__ be,
    const float* __restrict__ mm, const float* __restrict__ vv,
    float* __restrict__ outf, _Float16* __restrict__ outh) {
  const int C = HH * 256;
  const int n = blockIdx.x;
  const int tid = threadIdx.x;
  const int c0 = tid * 4;
  const int head = c0 >> 8;
  __shared__ int s_src[64];
  __shared__ float s_al[64 * HH];
  const float idn = 1.f / (den[n * HH + head] + 1e-16f);
  float4 acc = {0.f, 0.f, 0.f, 0.f};
  const int beg = rowptr[n], end = rowptr[n + 1];
  for (int base = beg; base < end; base += 64) {
    const int cnt = min(64, end - base);
    __syncthreads();
    if (tid < cnt) s_src[tid] = csr_src[base + tid];
    if (tid < cnt * HH) s_al[tid] = ewc[(size_t)base * HH + tid];
    __syncthreads();
    int j = 0;
    for (; j + 1 < cnt; j += 2) {
      const float w0 = s_al[j * HH + head];
      const float w1 = s_al[(j + 1) * HH + head];
      const half4 v0 = *(const half4*)(h + (size_t)s_src[j] * C + c0);
      const half4 v1 = *(const half4*)(h + (size_t)s_src[j + 1] * C + c0);
      acc.x += (float)v0[0] * w0 + (float)v1[0] * w1;
      acc.y += (float)v0[1] * w0 + (float)v1[1] * w1;
      acc.z += (float)v0[2] * w0 + (float)v1[2] * w1;
      acc.w += (float)v0[3] * w0 + (float)v1[3] * w1;
    }
    if (j < cnt) {
      const float w0 = s_al[j * HH + head];
      const half4 v0 = *(const half4*)(h + (size_t)s_src[j] * C + c0);
      acc.x += (float)v0[0] * w0;
      acc.y += (float)v0[1] * w0;
      acc.z += (float)v0[2] * w0;
      acc.w += (float)v0[3] * w0;
    }
  }
  float vals[4] = {acc.x * idn, acc.y * idn, acc.z * idn, acc.w * idn};
#pragma unroll
  for (int i = 0; i < 4; i++) {
    const int c = c0 + i;
    float val = vals[i] + bias[c];
    if (DO_BN) val = (val - mm[c]) * rsqrtf(vv[c] + BN_EPS) * gg[c] + be[c];
    val = val > 0.f ? val : expm1f(val);  // ELU
    if (outh) outh[(size_t)n * C + c] = (_Float16)val;
    else      outf[(size_t)n * C + c] = val;
  }
}

// ---------------------------------------------------------------------------
extern "C" void kernel_launch(void* const* d_in, const int* in_sizes, int n_in,
                              void* d_out, int out_size, void* d_ws,
                              size_t ws_size, hipStream_t stream) {
  const float* x    = (const float*)d_in[0];
  const int*   ei   = (const int*)d_in[1];
  const float* W1   = (const float*)d_in[2];
  const float* a1s  = (const float*)d_in[3];
  const float* a1d  = (const float*)d_in[4];
  const float* b1   = (const float*)d_in[5];
  const float* W2   = (const float*)d_in[6];
  const float* a2s  = (const float*)d_in[7];
  const float* a2d  = (const float*)d_in[8];
  const float* b2   = (const float*)d_in[9];
  const float* W3   = (const float*)d_in[10];
  const float* a3s  = (const float*)d_in[11];
  const float* a3d  = (const float*)d_in[12];
  const float* b3   = (const float*)d_in[13];
  const float* g1   = (const float*)d_in[14];
  const float* be1  = (const float*)d_in[15];
  const float* m1   = (const float*)d_in[16];
  const float* v1   = (const float*)d_in[17];
  const float* g2   = (const float*)d_in[18];
  const float* be2  = (const float*)d_in[19];
  const float* m2   = (const float*)d_in[20];
  const float* v2   = (const float*)d_in[21];
  const float* fc1W = (const float*)d_in[22];
  const float* fc1b = (const float*)d_in[23];
  const float* fc2W = (const float*)d_in[24];
  const float* fc2b = (const float*)d_in[25];
  float* out = (float*)d_out;

  char* p = (char*)d_ws;
  auto alloc = [&](size_t bytes) -> void* {
    void* r = (void*)p;
    p += (bytes + 255) & ~(size_t)255;
    return r;
  };
  _Float16* hA     = (_Float16*)alloc((size_t)M_PAD * C1 * 2);  // GEMM input (holds xh first)
  _Float16* hG     = (_Float16*)alloc((size_t)M_PAD * C1 * 2);  // GEMM output
  _Float16* wh     = (_Float16*)alloc((size_t)C1 * C1 * 2);
  float*    buf1   = (float*)alloc((size_t)N_NODES * DH * 4);   // agg3 out -> fc1 in
  float*    buf0   = (float*)alloc((size_t)N_NODES * 128 * 4);  // fc1 out
  float*    as_    = (float*)alloc((size_t)N_NODES * HEADS * 4);
  float*    ad_    = (float*)alloc((size_t)N_NODES * HEADS * 4);
  float*    den    = (float*)alloc((size_t)N_NODES * HEADS * 4);
  float*    ewc    = (float*)alloc((size_t)ETOT * HEADS * 4);
  int*      rowptr = (int*)alloc((size_t)(N_NODES + 1) * 4);
  int*      cnt    = (int*)alloc((size_t)N_NODES * 4);
  int*      csrS   = (int*)alloc((size_t)ETOT * 4);
  int*      einv   = (int*)alloc((size_t)ETOT * 4);

  const int eb = (ETOT + 255) / 256;
  _Float16* xh = hA;  // alias: [M_PAD][K1PAD]

  // ---- CSR build (graph identical for all three layers) ----
  hipMemsetAsync(cnt, 0, (size_t)N_NODES * 4, stream);
  k_count<<<eb, 256, 0, stream>>>(ei, cnt);
  k_scan<<<1, 256, 0, stream>>>(cnt, rowptr);
  hipMemsetAsync(cnt, 0, (size_t)N_NODES * 4, stream);
  k_fill<<<eb, 256, 0, stream>>>(ei, rowptr, cnt, csrS, einv);

  // ---- Layer 1: GATConv(300 -> 4x256) + BN1 + ELU ----
  k_cvt<<<(N_NODES * (K1PAD / 2) + 255) / 256, 256, 0, stream>>>(
      x, xh, N_NODES, F_INDIM, K1PAD);
  k_cvt<<<(C1 * (K1PAD / 2) + 255) / 256, 256, 0, stream>>>(
      W1, wh, C1, F_INDIM, K1PAD);
  k_mfma_gemm<1><<<dim3(C1 / 128, M_PAD / 128), 256, 0, stream>>>(
      xh, wh, nullptr, hG, N_NODES, C1, K1PAD);
  k_alpha<4><<<N_NODES, 256, 0, stream>>>(hG, a1s, a1d, as_, ad_);
  hipMemsetAsync(den, 0, (size_t)N_NODES * HEADS * 4, stream);
  k_edge<4><<<eb, 256, 0, stream>>>(ei, einv, ewc, den, as_, ad_);
  k_agg<4, true><<<N_NODES, 256, 0, stream>>>(hG, rowptr, csrS, ewc, den,
                                              b1, g1, be1, m1, v1, nullptr, hA);

  // ---- Layer 2: GATConv(1024 -> 4x256) + BN2 + ELU ----
  k_cvt<<<(C1 * (C1 / 2) + 255) / 256, 256, 0, stream>>>(W2, wh, C1, C1, C1);
  k_mfma_gemm<1><<<dim3(C1 / 128, M_PAD / 128), 256, 0, stream>>>(
      hA, wh, nullptr, hG, N_NODES, C1, C1);
  k_alpha<4><<<N_NODES, 256, 0, stream>>>(hG, a2s, a2d, as_, ad_);
  hipMemsetAsync(den, 0, (size_t)N_NODES * HEADS * 4, stream);
  k_edge<4><<<eb, 256, 0, stream>>>(ei, einv, ewc, den, as_, ad_);
  k_agg<4, true><<<N_NODES, 256, 0, stream>>>(hG, rowptr, csrS, ewc, den,
                                              b2, g2, be2, m2, v2, nullptr, hA);

  // ---- Layer 3: GATConv(1024 -> 256, heads=1) + ELU ----
  k_cvt<<<(DH * (C1 / 2) + 255) / 256, 256, 0, stream>>>(W3, wh, DH, C1, C1);
  k_mfma_gemm<1><<<dim3(DH / 128, M_PAD / 128), 256, 0, stream>>>(
      hA, wh, nullptr, hG, N_NODES, DH, C1);
  k_alpha<1><<<N_NODES, 64, 0, stream>>>(hG, a3s, a3d, as_, ad_);
  hipMemsetAsync(den, 0, (size_t)N_NODES * 4, stream);
  k_edge<1><<<eb, 256, 0, stream>>>(ei, einv, ewc, den, as_, ad_);
  k_agg<1, false><<<N_NODES, 64, 0, stream>>>(hG, rowptr, csrS, ewc, den,
                                              b3, nullptr, nullptr, nullptr,
                                              nullptr, buf1, nullptr);

  // ---- MLP head (fp32 path, small) ----
  k_gemm<1><<<dim3(1, (N_NODES + 127) / 128), 256, 0, stream>>>(
      buf1, fc1W, fc1b, buf0, N_NODES, 128, DH);
  k_gemm<0><<<dim3(1, (N_NODES + 127) / 128), 256, 0, stream>>>(
      buf0, fc2W, fc2b, out, N_NODES, NCLS, 128);
}

// Round 5
// 554.577 us; speedup vs baseline: 1.1535x; 1.1535x over previous
//
#include <hip/hip_runtime.h>
#include <cstdint>
#include <cstddef>

#define N_NODES 10000
#define M_PAD   10112            // 79 * 128
#define N_EDGES 160000
#define ETOT    (N_EDGES + N_NODES)   // with self-loops
#define F_INDIM 300
#define K1PAD   320              // F_INDIM padded to mult of 32
#define HEADS   4
#define DH      256
#define C1      (HEADS * DH)     // 1024
#define NCLS    6
#define BN_EPS  1e-5f

typedef _Float16 half8 __attribute__((ext_vector_type(8)));
typedef _Float16 half4 __attribute__((ext_vector_type(4)));
typedef float f32x4 __attribute__((ext_vector_type(4)));

__device__ __forceinline__ void gld_lds16(const void* g, void* s) {
  __builtin_amdgcn_global_load_lds(
      (const __attribute__((address_space(1))) void*)g,
      (__attribute__((address_space(3))) void*)s, 16, 0, 0);
}

// ---------------------------------------------------------------------------
// fp16 MFMA GEMM: C[M,Nn] = A[M,K]fp16 @ B[Nn,K]fp16^T  (NT)
// 128x128 tile, BK=32, 256 threads = 4 waves (2x2), 4x4 16x16x32 frags/wave.
// LDS linear [128][32] halves: frag ds_read_b128 is conflict-free (64B rows).
// OUT16=1 -> fp16 output, else fp32.
// ---------------------------------------------------------------------------
template <int OUT16>
__global__ __launch_bounds__(256) void k_mfma_gemm(
    const _Float16* __restrict__ A, const _Float16* __restrict__ B,
    float* __restrict__ Cf, _Float16* __restrict__ Ch,
    int M, int Nn, int K) {
  __shared__ __align__(16) _Float16 sA[128 * 32];
  __shared__ __align__(16) _Float16 sB[128 * 32];
  const int tid = threadIdx.x;
  const int lane = tid & 63, w = tid >> 6;
  const int wm = w >> 1, wn = w & 1;
  const int row0 = blockIdx.y * 128, col0 = blockIdx.x * 128;

  const int r_loc = lane >> 2;       // 0..15
  const int j8 = (lane & 3) * 8;     // half offset within BK=32
  const _Float16* gA = A + (size_t)(row0 + w * 32 + r_loc) * K + j8;
  const _Float16* gB = B + (size_t)(col0 + w * 32 + r_loc) * K + j8;
  _Float16* sAw = sA + (w * 32) * 32;
  _Float16* sBw = sB + (w * 32) * 32;

  const int fr = lane & 15, kb = lane >> 4;
  const _Float16* pA = sA + ((size_t)(wm * 64 + fr) * 32 + kb * 8);
  const _Float16* pB = sB + ((size_t)(wn * 64 + fr) * 32 + kb * 8);

  f32x4 acc[4][4] = {};
  const int KT = K / 32;

  {
    gld_lds16(gA, sAw);
    gld_lds16(gA + (size_t)16 * K, sAw + 16 * 32);
    gld_lds16(gB, sBw);
    gld_lds16(gB + (size_t)16 * K, sBw + 16 * 32);
  }
  for (int kt = 0; kt < KT; ++kt) {
    __syncthreads();
    half8 af[4], bf[4];
#pragma unroll
    for (int i = 0; i < 4; ++i) af[i] = *(const half8*)(pA + i * 16 * 32);
#pragma unroll
    for (int j = 0; j < 4; ++j) bf[j] = *(const half8*)(pB + j * 16 * 32);
    __syncthreads();
    if (kt + 1 < KT) {
      const _Float16* ga = gA + (size_t)(kt + 1) * 32;
      const _Float16* gb = gB + (size_t)(kt + 1) * 32;
      gld_lds16(ga, sAw);
      gld_lds16(ga + (size_t)16 * K, sAw + 16 * 32);
      gld_lds16(gb, sBw);
      gld_lds16(gb + (size_t)16 * K, sBw + 16 * 32);
    }
#pragma unroll
    for (int i = 0; i < 4; ++i)
#pragma unroll
      for (int j = 0; j < 4; ++j)
        acc[i][j] =
            __builtin_amdgcn_mfma_f32_16x16x32_f16(af[i], bf[j], acc[i][j], 0, 0, 0);
  }

  // C/D layout: col = lane&15, row = (lane>>4)*4 + reg
  const int orow = row0 + wm * 64 + kb * 4;
  const int ocol = col0 + wn * 64 + fr;
#pragma unroll
  for (int i = 0; i < 4; ++i) {
#pragma unroll
    for (int r = 0; r < 4; ++r) {
      const int rr = orow + i * 16 + r;
      if (rr >= M) continue;
#pragma unroll
      for (int j = 0; j < 4; ++j) {
        if (OUT16) Ch[(size_t)rr * Nn + ocol + j * 16] = (_Float16)acc[i][j][r];
        else       Cf[(size_t)rr * Nn + ocol + j * 16] = acc[i][j][r];
      }
    }
  }
}

// ---------------------------------------------------------------------------
// fp32 -> fp16 conversion with K padding (zeros for k >= K)
// ---------------------------------------------------------------------------
__global__ __launch_bounds__(256) void k_cvt(const float* __restrict__ in,
                                             _Float16* __restrict__ out,
                                             int M, int K, int Kpad) {
  const int idx = blockIdx.x * 256 + threadIdx.x;
  const int kp2 = Kpad >> 1;
  if (idx >= M * kp2) return;
  const int r = idx / kp2, c2 = (idx % kp2) * 2;
  const float vx = (c2 < K) ? in[(size_t)r * K + c2] : 0.f;
  const float vy = (c2 + 1 < K) ? in[(size_t)r * K + c2 + 1] : 0.f;
  out[(size_t)r * Kpad + c2] = (_Float16)vx;
  out[(size_t)r * Kpad + c2 + 1] = (_Float16)vy;
}

// ---------------------------------------------------------------------------
// Fused MLP head: out = fc2( relu( fc1(h) ) ), 8 nodes per block.
// fc1W [128,256], fc2W [6,128]. Grid = N/8 = 1250 blocks, 256 threads.
// Thread t: fc1 column j=t&127 for 4 nodes of group g=t>>7 (W row in regs,
// reused x4). fc2 by 48 threads from padded LDS (stride 132 -> no conflicts).
// ---------------------------------------------------------------------------
#define MLP_NPB 8
__global__ __launch_bounds__(256) void k_mlp(
    const float* __restrict__ h, const float* __restrict__ W1,
    const float* __restrict__ b1, const float* __restrict__ W2,
    const float* __restrict__ b2, float* __restrict__ out) {
  __shared__ float sh[MLP_NPB * 256];   // 8 input rows (8 KB)
  __shared__ float sy[MLP_NPB][132];    // relu(fc1) padded (4.2 KB)
  const int tid = threadIdx.x;
  const int n0 = blockIdx.x * MLP_NPB;
  {
    const float4* src = (const float4*)(h + (size_t)n0 * 256);
    float4* dst = (float4*)sh;
    dst[tid] = src[tid];
    dst[tid + 256] = src[tid + 256];
  }
  __syncthreads();
  const int j = tid & 127;   // fc1 output index
  const int g = tid >> 7;    // node group: nodes g*4 .. g*4+3
  const float bj = b1[j];
  float a0 = bj, a1 = bj, a2 = bj, a3 = bj;
  const float4* wrow = (const float4*)(W1 + (size_t)j * 256);
  const float4* h0 = (const float4*)(sh + (g * 4 + 0) * 256);
  const float4* h1 = (const float4*)(sh + (g * 4 + 1) * 256);
  const float4* h2 = (const float4*)(sh + (g * 4 + 2) * 256);
  const float4* h3 = (const float4*)(sh + (g * 4 + 3) * 256);
#pragma unroll 8
  for (int k = 0; k < 64; ++k) {
    const float4 w = wrow[k];
    const float4 v0 = h0[k], v1 = h1[k], v2 = h2[k], v3 = h3[k];
    a0 += w.x * v0.x + w.y * v0.y + w.z * v0.z + w.w * v0.w;
    a1 += w.x * v1.x + w.y * v1.y + w.z * v1.z + w.w * v1.w;
    a2 += w.x * v2.x + w.y * v2.y + w.z * v2.z + w.w * v2.w;
    a3 += w.x * v3.x + w.y * v3.y + w.z * v3.z + w.w * v3.w;
  }
  sy[g * 4 + 0][j] = a0 > 0.f ? a0 : 0.f;
  sy[g * 4 + 1][j] = a1 > 0.f ? a1 : 0.f;
  sy[g * 4 + 2][j] = a2 > 0.f ? a2 : 0.f;
  sy[g * 4 + 3][j] = a3 > 0.f ? a3 : 0.f;
  __syncthreads();
  if (tid < MLP_NPB * NCLS) {  // 48 threads
    const int n = tid / NCLS, c = tid % NCLS;
    float s = b2[c];
    const float* w2 = W2 + c * 128;
#pragma unroll 8
    for (int k = 0; k < 128; ++k) s += sy[n][k] * w2[k];
    out[(size_t)(n0 + n) * NCLS + c] = s;
  }
}

// ---------------------------------------------------------------------------
// alpha_s[n,h] = <h[n,h,:], a_src[h,:]> from fp16 h. Block = HH*64.
// ---------------------------------------------------------------------------
template <int HH>
__global__ __launch_bounds__(HH * 64) void k_alpha(
    const _Float16* __restrict__ h, const float* __restrict__ a_src,
    const float* __restrict__ a_dst, float* __restrict__ as_,
    float* __restrict__ ad_) {
  const int n = blockIdx.x;
  const int tid = threadIdx.x;
  const int head = tid >> 6;
  const int lane = tid & 63;
  const half4 hv = *(const half4*)(h + (size_t)n * HH * DH + head * DH + lane * 4);
  const float4 sv = *(reinterpret_cast<const float4*>(a_src + head * DH) + lane);
  const float4 dv = *(reinterpret_cast<const float4*>(a_dst + head * DH) + lane);
  const float h0 = (float)hv[0], h1 = (float)hv[1], h2 = (float)hv[2],
              h3 = (float)hv[3];
  float s1 = h0 * sv.x + h1 * sv.y + h2 * sv.z + h3 * sv.w;
  float s2 = h0 * dv.x + h1 * dv.y + h2 * dv.z + h3 * dv.w;
#pragma unroll
  for (int off = 32; off > 0; off >>= 1) {
    s1 += __shfl_down(s1, off);
    s2 += __shfl_down(s2, off);
  }
  if (lane == 0) {
    as_[n * HH + head] = s1;
    ad_[n * HH + head] = s2;
  }
}

// ---------------------------------------------------------------------------
// Per edge: all heads. w = exp(leaky_relu(as[src]+ad[dst])); write into CSR
// slot order (einv) so aggregation reads weights contiguously.
// ---------------------------------------------------------------------------
template <int HH>
__global__ __launch_bounds__(256) void k_edge(
    const int* __restrict__ ei, const int* __restrict__ einv,
    float* __restrict__ ewc, float* __restrict__ den,
    const float* __restrict__ as_, const float* __restrict__ ad_) {
  const int e = blockIdx.x * 256 + threadIdx.x;
  if (e >= ETOT) return;
  int s, t;
  if (e < N_EDGES) { s = ei[e]; t = ei[N_EDGES + e]; }
  else             { s = t = e - N_EDGES; }
  const int pos = einv[e];
#pragma unroll
  for (int hh = 0; hh < HH; ++hh) {
    float x = as_[s * HH + hh] + ad_[t * HH + hh];
    x = x > 0.f ? x : 0.2f * x;
    const float w = expf(x);
    ewc[(size_t)pos * HH + hh] = w;
    atomicAdd(&den[t * HH + hh], w);
  }
}

// ---------------------------------------------------------------------------
// CSR build
// ---------------------------------------------------------------------------
__global__ __launch_bounds__(256) void k_count(const int* __restrict__ ei,
                                               int* __restrict__ cnt) {
  const int e = blockIdx.x * 256 + threadIdx.x;
  if (e >= ETOT) return;
  const int t = (e < N_EDGES) ? ei[N_EDGES + e] : (e - N_EDGES);
  atomicAdd(&cnt[t], 1);
}

__global__ __launch_bounds__(256) void k_scan(const int* __restrict__ cnt,
                                              int* __restrict__ rowptr) {
  __shared__ int part[256];
  const int tid = threadIdx.x;
  const int chunk = (N_NODES + 255) / 256;  // 40
  const int b = tid * chunk;
  int sum = 0;
  for (int i = 0; i < chunk; i++) {
    const int idx = b + i;
    if (idx < N_NODES) sum += cnt[idx];
  }
  part[tid] = sum;
  __syncthreads();
  for (int off = 1; off < 256; off <<= 1) {
    int t2 = (tid >= off) ? part[tid - off] : 0;
    __syncthreads();
    part[tid] += t2;
    __syncthreads();
  }
  int run = part[tid] - sum;
  for (int i = 0; i < chunk; i++) {
    const int idx = b + i;
    if (idx < N_NODES) {
      rowptr[idx] = run;
      run += cnt[idx];
    }
  }
  if (tid == 255) rowptr[N_NODES] = part[255];
}

__global__ __launch_bounds__(256) void k_fill(
    const int* __restrict__ ei, const int* __restrict__ rowptr,
    int* __restrict__ fill, int* __restrict__ csr_src,
    int* __restrict__ einv) {
  const int e = blockIdx.x * 256 + threadIdx.x;
  if (e >= ETOT) return;
  int s, t;
  if (e < N_EDGES) { s = ei[e]; t = ei[N_EDGES + e]; }
  else             { s = t = e - N_EDGES; }
  const int pos = rowptr[t] + atomicAdd(&fill[t], 1);
  csr_src[pos] = s;
  einv[e] = pos;
}

// ---------------------------------------------------------------------------
// Aggregation from fp16 h: out[n] = epilogue( sum alpha_e * h[src_e] )
// ewc is CSR-slot-ordered -> contiguous weight reads.
// Writes fp16 (outh) or fp32 (outf).
// ---------------------------------------------------------------------------
template <int HH, bool DO_BN>
__global__ __launch_bounds__(HH * 64) void k_agg(
    const _Float16* __restrict__ h, const int* __restrict__ rowptr,
    const int* __restrict__ csr_src, const float* __restrict__ ewc,
    const float* __restrict__ den, const float* __restrict__ bias,
    const float* __restrict__ gg, const float* __restrict__ be,
    const float* __restrict__ mm, const float* __restrict__ vv,
    float* __restrict__ outf, _Float16* __restrict__ outh) {
  const int C = HH * 256;
  const int n = blockIdx.x;
  const int tid = threadIdx.x;
  const int c0 = tid * 4;
  const int head = c0 >> 8;
  __shared__ int s_src[64];
  __shared__ float s_al[64 * HH];
  const float idn = 1.f / (den[n * HH + head] + 1e-16f);
  float4 acc = {0.f, 0.f, 0.f, 0.f};
  const int beg = rowptr[n], end = rowptr[n + 1];
  for (int base = beg; base < end; base += 64) {
    const int cnt = min(64, end - base);
    __syncthreads();
    if (tid < cnt) s_src[tid] = csr_src[base + tid];
    if (tid < cnt * HH) s_al[tid] = ewc[(size_t)base * HH + tid];
    __syncthreads();
    int j = 0;
    for (; j + 1 < cnt; j += 2) {
      const float w0 = s_al[j * HH + head];
      const float w1 = s_al[(j + 1) * HH + head];
      const half4 v0 = *(const half4*)(h + (size_t)s_src[j] * C + c0);
      const half4 v1 = *(const half4*)(h + (size_t)s_src[j + 1] * C + c0);
      acc.x += (float)v0[0] * w0 + (float)v1[0] * w1;
      acc.y += (float)v0[1] * w0 + (float)v1[1] * w1;
      acc.z += (float)v0[2] * w0 + (float)v1[2] * w1;
      acc.w += (float)v0[3] * w0 + (float)v1[3] * w1;
    }
    if (j < cnt) {
      const float w0 = s_al[j * HH + head];
      const half4 v0 = *(const half4*)(h + (size_t)s_src[j] * C + c0);
      acc.x += (float)v0[0] * w0;
      acc.y += (float)v0[1] * w0;
      acc.z += (float)v0[2] * w0;
      acc.w += (float)v0[3] * w0;
    }
  }
  float vals[4] = {acc.x * idn, acc.y * idn, acc.z * idn, acc.w * idn};
#pragma unroll
  for (int i = 0; i < 4; i++) {
    const int c = c0 + i;
    float val = vals[i] + bias[c];
    if (DO_BN) val = (val - mm[c]) * rsqrtf(vv[c] + BN_EPS) * gg[c] + be[c];
    val = val > 0.f ? val : expm1f(val);  // ELU
    if (outh) outh[(size_t)n * C + c] = (_Float16)val;
    else      outf[(size_t)n * C + c] = val;
  }
}

// ---------------------------------------------------------------------------
extern "C" void kernel_launch(void* const* d_in, const int* in_sizes, int n_in,
                              void* d_out, int out_size, void* d_ws,
                              size_t ws_size, hipStream_t stream) {
  const float* x    = (const float*)d_in[0];
  const int*   ei   = (const int*)d_in[1];
  const float* W1   = (const float*)d_in[2];
  const float* a1s  = (const float*)d_in[3];
  const float* a1d  = (const float*)d_in[4];
  const float* b1   = (const float*)d_in[5];
  const float* W2   = (const float*)d_in[6];
  const float* a2s  = (const float*)d_in[7];
  const float* a2d  = (const float*)d_in[8];
  const float* b2   = (const float*)d_in[9];
  const float* W3   = (const float*)d_in[10];
  const float* a3s  = (const float*)d_in[11];
  const float* a3d  = (const float*)d_in[12];
  const float* b3   = (const float*)d_in[13];
  const float* g1   = (const float*)d_in[14];
  const float* be1  = (const float*)d_in[15];
  const float* m1   = (const float*)d_in[16];
  const float* v1   = (const float*)d_in[17];
  const float* g2   = (const float*)d_in[18];
  const float* be2  = (const float*)d_in[19];
  const float* m2   = (const float*)d_in[20];
  const float* v2   = (const float*)d_in[21];
  const float* fc1W = (const float*)d_in[22];
  const float* fc1b = (const float*)d_in[23];
  const float* fc2W = (const float*)d_in[24];
  const float* fc2b = (const float*)d_in[25];
  float* out = (float*)d_out;

  char* p = (char*)d_ws;
  auto alloc = [&](size_t bytes) -> void* {
    void* r = (void*)p;
    p += (bytes + 255) & ~(size_t)255;
    return r;
  };
  _Float16* hA     = (_Float16*)alloc((size_t)M_PAD * C1 * 2);  // GEMM input (holds xh first)
  _Float16* hG     = (_Float16*)alloc((size_t)M_PAD * C1 * 2);  // GEMM output
  _Float16* wh     = (_Float16*)alloc((size_t)C1 * C1 * 2);
  float*    buf1   = (float*)alloc((size_t)N_NODES * DH * 4);   // agg3 out -> MLP in
  float*    as_    = (float*)alloc((size_t)N_NODES * HEADS * 4);
  float*    ad_    = (float*)alloc((size_t)N_NODES * HEADS * 4);
  float*    den    = (float*)alloc((size_t)N_NODES * HEADS * 4);
  float*    ewc    = (float*)alloc((size_t)ETOT * HEADS * 4);
  int*      rowptr = (int*)alloc((size_t)(N_NODES + 1) * 4);
  int*      cnt    = (int*)alloc((size_t)N_NODES * 4);
  int*      csrS   = (int*)alloc((size_t)ETOT * 4);
  int*      einv   = (int*)alloc((size_t)ETOT * 4);

  const int eb = (ETOT + 255) / 256;
  _Float16* xh = hA;  // alias: [M_PAD][K1PAD]

  // ---- CSR build (graph identical for all three layers) ----
  hipMemsetAsync(cnt, 0, (size_t)N_NODES * 4, stream);
  k_count<<<eb, 256, 0, stream>>>(ei, cnt);
  k_scan<<<1, 256, 0, stream>>>(cnt, rowptr);
  hipMemsetAsync(cnt, 0, (size_t)N_NODES * 4, stream);
  k_fill<<<eb, 256, 0, stream>>>(ei, rowptr, cnt, csrS, einv);

  // ---- Layer 1: GATConv(300 -> 4x256) + BN1 + ELU ----
  k_cvt<<<(N_NODES * (K1PAD / 2) + 255) / 256, 256, 0, stream>>>(
      x, xh, N_NODES, F_INDIM, K1PAD);
  k_cvt<<<(C1 * (K1PAD / 2) + 255) / 256, 256, 0, stream>>>(
      W1, wh, C1, F_INDIM, K1PAD);
  k_mfma_gemm<1><<<dim3(C1 / 128, M_PAD / 128), 256, 0, stream>>>(
      xh, wh, nullptr, hG, N_NODES, C1, K1PAD);
  k_alpha<4><<<N_NODES, 256, 0, stream>>>(hG, a1s, a1d, as_, ad_);
  hipMemsetAsync(den, 0, (size_t)N_NODES * HEADS * 4, stream);
  k_edge<4><<<eb, 256, 0, stream>>>(ei, einv, ewc, den, as_, ad_);
  k_agg<4, true><<<N_NODES, 256, 0, stream>>>(hG, rowptr, csrS, ewc, den,
                                              b1, g1, be1, m1, v1, nullptr, hA);

  // ---- Layer 2: GATConv(1024 -> 4x256) + BN2 + ELU ----
  k_cvt<<<(C1 * (C1 / 2) + 255) / 256, 256, 0, stream>>>(W2, wh, C1, C1, C1);
  k_mfma_gemm<1><<<dim3(C1 / 128, M_PAD / 128), 256, 0, stream>>>(
      hA, wh, nullptr, hG, N_NODES, C1, C1);
  k_alpha<4><<<N_NODES, 256, 0, stream>>>(hG, a2s, a2d, as_, ad_);
  hipMemsetAsync(den, 0, (size_t)N_NODES * HEADS * 4, stream);
  k_edge<4><<<eb, 256, 0, stream>>>(ei, einv, ewc, den, as_, ad_);
  k_agg<4, true><<<N_NODES, 256, 0, stream>>>(hG, rowptr, csrS, ewc, den,
                                              b2, g2, be2, m2, v2, nullptr, hA);

  // ---- Layer 3: GATConv(1024 -> 256, heads=1) + ELU ----
  k_cvt<<<(DH * (C1 / 2) + 255) / 256, 256, 0, stream>>>(W3, wh, DH, C1, C1);
  k_mfma_gemm<1><<<dim3(DH / 128, M_PAD / 128), 256, 0, stream>>>(
      hA, wh, nullptr, hG, N_NODES, DH, C1);
  k_alpha<1><<<N_NODES, 64, 0, stream>>>(hG, a3s, a3d, as_, ad_);
  hipMemsetAsync(den, 0, (size_t)N_NODES * 4, stream);
  k_edge<1><<<eb, 256, 0, stream>>>(ei, einv, ewc, den, as_, ad_);
  k_agg<1, false><<<N_NODES, 64, 0, stream>>>(hG, rowptr, csrS, ewc, den,
                                              b3, nullptr, nullptr, nullptr,
                                              nullptr, buf1, nullptr);

  // ---- Fused MLP head ----
  k_mlp<<<N_NODES / MLP_NPB, 256, 0, stream>>>(buf1, fc1W, fc1b, fc2W, fc2b,
                                               out);
}

// Round 6
// 550.362 us; speedup vs baseline: 1.1624x; 1.0077x over previous
//
#include <hip/hip_runtime.h>
#include <cstdint>
#include <cstddef>

#define N_NODES 10000
#define M_PAD   10112            // 79 * 128
#define N_EDGES 160000
#define ETOT    (N_EDGES + N_NODES)   // with self-loops
#define F_INDIM 300
#define K1PAD   320              // F_INDIM padded to mult of 32
#define HEADS   4
#define DH      256
#define C1      (HEADS * DH)     // 1024
#define NCLS    6
#define BN_EPS  1e-5f

typedef _Float16 half8 __attribute__((ext_vector_type(8)));
typedef _Float16 half4 __attribute__((ext_vector_type(4)));
typedef float f32x4 __attribute__((ext_vector_type(4)));

__device__ __forceinline__ void gld_lds16(const void* g, void* s) {
  __builtin_amdgcn_global_load_lds(
      (const __attribute__((address_space(1))) void*)g,
      (__attribute__((address_space(3))) void*)s, 16, 0, 0);
}

// ---------------------------------------------------------------------------
// fp16 MFMA GEMM: C[M,Nn] = A[M,K]fp16 @ B[Nn,K]fp16^T  (NT)
// 128x128 tile, BK=32, 256 threads = 4 waves (2x2), 4x4 16x16x32 frags/wave.
// LDS linear [128][32] halves: frag ds_read_b128 is conflict-free (64B rows).
// OUT16=1 -> fp16 output, else fp32.
// ---------------------------------------------------------------------------
template <int OUT16>
__global__ __launch_bounds__(256) void k_mfma_gemm(
    const _Float16* __restrict__ A, const _Float16* __restrict__ B,
    float* __restrict__ Cf, _Float16* __restrict__ Ch,
    int M, int Nn, int K) {
  __shared__ __align__(16) _Float16 sA[128 * 32];
  __shared__ __align__(16) _Float16 sB[128 * 32];
  const int tid = threadIdx.x;
  const int lane = tid & 63, w = tid >> 6;
  const int wm = w >> 1, wn = w & 1;
  const int row0 = blockIdx.y * 128, col0 = blockIdx.x * 128;

  const int r_loc = lane >> 2;       // 0..15
  const int j8 = (lane & 3) * 8;     // half offset within BK=32
  const _Float16* gA = A + (size_t)(row0 + w * 32 + r_loc) * K + j8;
  const _Float16* gB = B + (size_t)(col0 + w * 32 + r_loc) * K + j8;
  _Float16* sAw = sA + (w * 32) * 32;
  _Float16* sBw = sB + (w * 32) * 32;

  const int fr = lane & 15, kb = lane >> 4;
  const _Float16* pA = sA + ((size_t)(wm * 64 + fr) * 32 + kb * 8);
  const _Float16* pB = sB + ((size_t)(wn * 64 + fr) * 32 + kb * 8);

  f32x4 acc[4][4] = {};
  const int KT = K / 32;

  {
    gld_lds16(gA, sAw);
    gld_lds16(gA + (size_t)16 * K, sAw + 16 * 32);
    gld_lds16(gB, sBw);
    gld_lds16(gB + (size_t)16 * K, sBw + 16 * 32);
  }
  for (int kt = 0; kt < KT; ++kt) {
    __syncthreads();
    half8 af[4], bf[4];
#pragma unroll
    for (int i = 0; i < 4; ++i) af[i] = *(const half8*)(pA + i * 16 * 32);
#pragma unroll
    for (int j = 0; j < 4; ++j) bf[j] = *(const half8*)(pB + j * 16 * 32);
    __syncthreads();
    if (kt + 1 < KT) {
      const _Float16* ga = gA + (size_t)(kt + 1) * 32;
      const _Float16* gb = gB + (size_t)(kt + 1) * 32;
      gld_lds16(ga, sAw);
      gld_lds16(ga + (size_t)16 * K, sAw + 16 * 32);
      gld_lds16(gb, sBw);
      gld_lds16(gb + (size_t)16 * K, sBw + 16 * 32);
    }
#pragma unroll
    for (int i = 0; i < 4; ++i)
#pragma unroll
      for (int j = 0; j < 4; ++j)
        acc[i][j] =
            __builtin_amdgcn_mfma_f32_16x16x32_f16(af[i], bf[j], acc[i][j], 0, 0, 0);
  }

  // C/D layout: col = lane&15, row = (lane>>4)*4 + reg
  const int orow = row0 + wm * 64 + kb * 4;
  const int ocol = col0 + wn * 64 + fr;
#pragma unroll
  for (int i = 0; i < 4; ++i) {
#pragma unroll
    for (int r = 0; r < 4; ++r) {
      const int rr = orow + i * 16 + r;
      if (rr >= M) continue;
#pragma unroll
      for (int j = 0; j < 4; ++j) {
        if (OUT16) Ch[(size_t)rr * Nn + ocol + j * 16] = (_Float16)acc[i][j][r];
        else       Cf[(size_t)rr * Nn + ocol + j * 16] = acc[i][j][r];
      }
    }
  }
}

// ---------------------------------------------------------------------------
// fp32 -> fp16 conversion with K padding (zeros for k >= K)
// ---------------------------------------------------------------------------
__global__ __launch_bounds__(256) void k_cvt(const float* __restrict__ in,
                                             _Float16* __restrict__ out,
                                             int M, int K, int Kpad) {
  const int idx = blockIdx.x * 256 + threadIdx.x;
  const int kp2 = Kpad >> 1;
  if (idx >= M * kp2) return;
  const int r = idx / kp2, c2 = (idx % kp2) * 2;
  const float vx = (c2 < K) ? in[(size_t)r * K + c2] : 0.f;
  const float vy = (c2 + 1 < K) ? in[(size_t)r * K + c2 + 1] : 0.f;
  out[(size_t)r * Kpad + c2] = (_Float16)vx;
  out[(size_t)r * Kpad + c2 + 1] = (_Float16)vy;
}

// ---------------------------------------------------------------------------
// Fused MLP head: out = fc2( relu( fc1(h) ) ), 8 nodes per block.
// ---------------------------------------------------------------------------
#define MLP_NPB 8
__global__ __launch_bounds__(256) void k_mlp(
    const float* __restrict__ h, const float* __restrict__ W1,
    const float* __restrict__ b1, const float* __restrict__ W2,
    const float* __restrict__ b2, float* __restrict__ out) {
  __shared__ float sh[MLP_NPB * 256];   // 8 input rows (8 KB)
  __shared__ float sy[MLP_NPB][132];    // relu(fc1) padded (4.2 KB)
  const int tid = threadIdx.x;
  const int n0 = blockIdx.x * MLP_NPB;
  {
    const float4* src = (const float4*)(h + (size_t)n0 * 256);
    float4* dst = (float4*)sh;
    dst[tid] = src[tid];
    dst[tid + 256] = src[tid + 256];
  }
  __syncthreads();
  const int j = tid & 127;   // fc1 output index
  const int g = tid >> 7;    // node group: nodes g*4 .. g*4+3
  const float bj = b1[j];
  float a0 = bj, a1 = bj, a2 = bj, a3 = bj;
  const float4* wrow = (const float4*)(W1 + (size_t)j * 256);
  const float4* h0 = (const float4*)(sh + (g * 4 + 0) * 256);
  const float4* h1 = (const float4*)(sh + (g * 4 + 1) * 256);
  const float4* h2 = (const float4*)(sh + (g * 4 + 2) * 256);
  const float4* h3 = (const float4*)(sh + (g * 4 + 3) * 256);
#pragma unroll 8
  for (int k = 0; k < 64; ++k) {
    const float4 w = wrow[k];
    const float4 v0 = h0[k], v1 = h1[k], v2 = h2[k], v3 = h3[k];
    a0 += w.x * v0.x + w.y * v0.y + w.z * v0.z + w.w * v0.w;
    a1 += w.x * v1.x + w.y * v1.y + w.z * v1.z + w.w * v1.w;
    a2 += w.x * v2.x + w.y * v2.y + w.z * v2.z + w.w * v2.w;
    a3 += w.x * v3.x + w.y * v3.y + w.z * v3.z + w.w * v3.w;
  }
  sy[g * 4 + 0][j] = a0 > 0.f ? a0 : 0.f;
  sy[g * 4 + 1][j] = a1 > 0.f ? a1 : 0.f;
  sy[g * 4 + 2][j] = a2 > 0.f ? a2 : 0.f;
  sy[g * 4 + 3][j] = a3 > 0.f ? a3 : 0.f;
  __syncthreads();
  if (tid < MLP_NPB * NCLS) {  // 48 threads
    const int n = tid / NCLS, c = tid % NCLS;
    float s = b2[c];
    const float* w2 = W2 + c * 128;
#pragma unroll 8
    for (int k = 0; k < 128; ++k) s += sy[n][k] * w2[k];
    out[(size_t)(n0 + n) * NCLS + c] = s;
  }
}

// ---------------------------------------------------------------------------
// alpha_s[n,h] = <h[n,h,:], a_src[h,:]> from fp16 h. Block = HH*64.
// ---------------------------------------------------------------------------
template <int HH>
__global__ __launch_bounds__(HH * 64) void k_alpha(
    const _Float16* __restrict__ h, const float* __restrict__ a_src,
    const float* __restrict__ a_dst, float* __restrict__ as_,
    float* __restrict__ ad_) {
  const int n = blockIdx.x;
  const int tid = threadIdx.x;
  const int head = tid >> 6;
  const int lane = tid & 63;
  const half4 hv = *(const half4*)(h + (size_t)n * HH * DH + head * DH + lane * 4);
  const float4 sv = *(reinterpret_cast<const float4*>(a_src + head * DH) + lane);
  const float4 dv = *(reinterpret_cast<const float4*>(a_dst + head * DH) + lane);
  const float h0 = (float)hv[0], h1 = (float)hv[1], h2 = (float)hv[2],
              h3 = (float)hv[3];
  float s1 = h0 * sv.x + h1 * sv.y + h2 * sv.z + h3 * sv.w;
  float s2 = h0 * dv.x + h1 * dv.y + h2 * dv.z + h3 * dv.w;
#pragma unroll
  for (int off = 32; off > 0; off >>= 1) {
    s1 += __shfl_down(s1, off);
    s2 += __shfl_down(s2, off);
  }
  if (lane == 0) {
    as_[n * HH + head] = s1;
    ad_[n * HH + head] = s2;
  }
}

// ---------------------------------------------------------------------------
// Per edge: all heads. w = exp(leaky_relu(as[src]+ad[dst])); write into CSR
// slot order (einv) so aggregation reads weights contiguously.
// ---------------------------------------------------------------------------
template <int HH>
__global__ __launch_bounds__(256) void k_edge(
    const int* __restrict__ ei, const int* __restrict__ einv,
    float* __restrict__ ewc, float* __restrict__ den,
    const float* __restrict__ as_, const float* __restrict__ ad_) {
  const int e = blockIdx.x * 256 + threadIdx.x;
  if (e >= ETOT) return;
  int s, t;
  if (e < N_EDGES) { s = ei[e]; t = ei[N_EDGES + e]; }
  else             { s = t = e - N_EDGES; }
  const int pos = einv[e];
#pragma unroll
  for (int hh = 0; hh < HH; ++hh) {
    float x = as_[s * HH + hh] + ad_[t * HH + hh];
    x = x > 0.f ? x : 0.2f * x;
    const float w = expf(x);
    ewc[(size_t)pos * HH + hh] = w;
    atomicAdd(&den[t * HH + hh], w);
  }
}

// ---------------------------------------------------------------------------
// CSR build
// ---------------------------------------------------------------------------
__global__ __launch_bounds__(256) void k_count(const int* __restrict__ ei,
                                               int* __restrict__ cnt) {
  const int e = blockIdx.x * 256 + threadIdx.x;
  if (e >= ETOT) return;
  const int t = (e < N_EDGES) ? ei[N_EDGES + e] : (e - N_EDGES);
  atomicAdd(&cnt[t], 1);
}

__global__ __launch_bounds__(256) void k_scan(const int* __restrict__ cnt,
                                              int* __restrict__ rowptr) {
  __shared__ int part[256];
  const int tid = threadIdx.x;
  const int chunk = (N_NODES + 255) / 256;  // 40
  const int b = tid * chunk;
  int sum = 0;
  for (int i = 0; i < chunk; i++) {
    const int idx = b + i;
    if (idx < N_NODES) sum += cnt[idx];
  }
  part[tid] = sum;
  __syncthreads();
  for (int off = 1; off < 256; off <<= 1) {
    int t2 = (tid >= off) ? part[tid - off] : 0;
    __syncthreads();
    part[tid] += t2;
    __syncthreads();
  }
  int run = part[tid] - sum;
  for (int i = 0; i < chunk; i++) {
    const int idx = b + i;
    if (idx < N_NODES) {
      rowptr[idx] = run;
      run += cnt[idx];
    }
  }
  if (tid == 255) rowptr[N_NODES] = part[255];
}

__global__ __launch_bounds__(256) void k_fill(
    const int* __restrict__ ei, const int* __restrict__ rowptr,
    int* __restrict__ fill, int* __restrict__ csr_src,
    int* __restrict__ einv) {
  const int e = blockIdx.x * 256 + threadIdx.x;
  if (e >= ETOT) return;
  int s, t;
  if (e < N_EDGES) { s = ei[e]; t = ei[N_EDGES + e]; }
  else             { s = t = e - N_EDGES; }
  const int pos = rowptr[t] + atomicAdd(&fill[t], 1);
  csr_src[pos] = s;
  einv[e] = pos;
}

// ---------------------------------------------------------------------------
// Aggregation from fp16 h: out[n] = epilogue( sum alpha_e * h[src_e] )
// ewc is CSR-slot-ordered -> contiguous weight reads.
// 8-deep unrolled gather: 8 independent half4 loads in flight per thread
// (round-5 profile: VGPR=16, VALUBusy 31%, HBM 26% -> latency-bound, MLP=2).
// ---------------------------------------------------------------------------
template <int HH, bool DO_BN>
__global__ __launch_bounds__(HH * 64) void k_agg(
    const _Float16* __restrict__ h, const int* __restrict__ rowptr,
    const int* __restrict__ csr_src, const float* __restrict__ ewc,
    const float* __restrict__ den, const float* __restrict__ bias,
    const float* __restrict__ gg, const float* __restrict__ be,
    const float* __restrict__ mm, const float* __restrict__ vv,
    float* __restrict__ outf, _Float16* __restrict__ outh) {
  const int C = HH * 256;
  const int n = blockIdx.x;
  const int tid = threadIdx.x;
  const int c0 = tid * 4;
  const int head = c0 >> 8;
  __shared__ int s_src[64];
  __shared__ float s_al[64 * HH];
  const float idn = 1.f / (den[n * HH + head] + 1e-16f);
  float4 acc = {0.f, 0.f, 0.f, 0.f};
  const int beg = rowptr[n], end = rowptr[n + 1];
  for (int base = beg; base < end; base += 64) {
    const int cnt = min(64, end - base);
    __syncthreads();
    if (tid < cnt) s_src[tid] = csr_src[base + tid];
    if (tid < cnt * HH) s_al[tid] = ewc[(size_t)base * HH + tid];
    __syncthreads();
    int j = 0;
    const int nfull = cnt & ~7;
    for (; j < nfull; j += 8) {
      float w[8];
      half4 v[8];
#pragma unroll
      for (int u = 0; u < 8; ++u) {
        w[u] = s_al[(j + u) * HH + head];
        v[u] = *(const half4*)(h + (size_t)s_src[j + u] * C + c0);
      }
#pragma unroll
      for (int u = 0; u < 8; ++u) {
        acc.x += (float)v[u][0] * w[u];
        acc.y += (float)v[u][1] * w[u];
        acc.z += (float)v[u][2] * w[u];
        acc.w += (float)v[u][3] * w[u];
      }
    }
    for (; j < cnt; ++j) {
      const float w0 = s_al[j * HH + head];
      const half4 v0 = *(const half4*)(h + (size_t)s_src[j] * C + c0);
      acc.x += (float)v0[0] * w0;
      acc.y += (float)v0[1] * w0;
      acc.z += (float)v0[2] * w0;
      acc.w += (float)v0[3] * w0;
    }
  }
  float vals[4] = {acc.x * idn, acc.y * idn, acc.z * idn, acc.w * idn};
#pragma unroll
  for (int i = 0; i < 4; i++) {
    const int c = c0 + i;
    float val = vals[i] + bias[c];
    if (DO_BN) val = (val - mm[c]) * rsqrtf(vv[c] + BN_EPS) * gg[c] + be[c];
    val = val > 0.f ? val : expm1f(val);  // ELU
    if (outh) outh[(size_t)n * C + c] = (_Float16)val;
    else      outf[(size_t)n * C + c] = val;
  }
}

// ---------------------------------------------------------------------------
extern "C" void kernel_launch(void* const* d_in, const int* in_sizes, int n_in,
                              void* d_out, int out_size, void* d_ws,
                              size_t ws_size, hipStream_t stream) {
  const float* x    = (const float*)d_in[0];
  const int*   ei   = (const int*)d_in[1];
  const float* W1   = (const float*)d_in[2];
  const float* a1s  = (const float*)d_in[3];
  const float* a1d  = (const float*)d_in[4];
  const float* b1   = (const float*)d_in[5];
  const float* W2   = (const float*)d_in[6];
  const float* a2s  = (const float*)d_in[7];
  const float* a2d  = (const float*)d_in[8];
  const float* b2   = (const float*)d_in[9];
  const float* W3   = (const float*)d_in[10];
  const float* a3s  = (const float*)d_in[11];
  const float* a3d  = (const float*)d_in[12];
  const float* b3   = (const float*)d_in[13];
  const float* g1   = (const float*)d_in[14];
  const float* be1  = (const float*)d_in[15];
  const float* m1   = (const float*)d_in[16];
  const float* v1   = (const float*)d_in[17];
  const float* g2   = (const float*)d_in[18];
  const float* be2  = (const float*)d_in[19];
  const float* m2   = (const float*)d_in[20];
  const float* v2   = (const float*)d_in[21];
  const float* fc1W = (const float*)d_in[22];
  const float* fc1b = (const float*)d_in[23];
  const float* fc2W = (const float*)d_in[24];
  const float* fc2b = (const float*)d_in[25];
  float* out = (float*)d_out;

  char* p = (char*)d_ws;
  auto alloc = [&](size_t bytes) -> void* {
    void* r = (void*)p;
    p += (bytes + 255) & ~(size_t)255;
    return r;
  };
  _Float16* hA     = (_Float16*)alloc((size_t)M_PAD * C1 * 2);  // GEMM input (holds xh first)
  _Float16* hG     = (_Float16*)alloc((size_t)M_PAD * C1 * 2);  // GEMM output
  _Float16* wh     = (_Float16*)alloc((size_t)C1 * C1 * 2);
  float*    buf1   = (float*)alloc((size_t)N_NODES * DH * 4);   // agg3 out -> MLP in
  float*    as_    = (float*)alloc((size_t)N_NODES * HEADS * 4);
  float*    ad_    = (float*)alloc((size_t)N_NODES * HEADS * 4);
  float*    den    = (float*)alloc((size_t)N_NODES * HEADS * 4);
  float*    ewc    = (float*)alloc((size_t)ETOT * HEADS * 4);
  int*      rowptr = (int*)alloc((size_t)(N_NODES + 1) * 4);
  int*      cnt    = (int*)alloc((size_t)N_NODES * 4);
  int*      csrS   = (int*)alloc((size_t)ETOT * 4);
  int*      einv   = (int*)alloc((size_t)ETOT * 4);

  const int eb = (ETOT + 255) / 256;
  _Float16* xh = hA;  // alias: [M_PAD][K1PAD]

  // ---- CSR build (graph identical for all three layers) ----
  hipMemsetAsync(cnt, 0, (size_t)N_NODES * 4, stream);
  k_count<<<eb, 256, 0, stream>>>(ei, cnt);
  k_scan<<<1, 256, 0, stream>>>(cnt, rowptr);
  hipMemsetAsync(cnt, 0, (size_t)N_NODES * 4, stream);
  k_fill<<<eb, 256, 0, stream>>>(ei, rowptr, cnt, csrS, einv);

  // ---- Layer 1: GATConv(300 -> 4x256) + BN1 + ELU ----
  k_cvt<<<(N_NODES * (K1PAD / 2) + 255) / 256, 256, 0, stream>>>(
      x, xh, N_NODES, F_INDIM, K1PAD);
  k_cvt<<<(C1 * (K1PAD / 2) + 255) / 256, 256, 0, stream>>>(
      W1, wh, C1, F_INDIM, K1PAD);
  k_mfma_gemm<1><<<dim3(C1 / 128, M_PAD / 128), 256, 0, stream>>>(
      xh, wh, nullptr, hG, N_NODES, C1, K1PAD);
  k_alpha<4><<<N_NODES, 256, 0, stream>>>(hG, a1s, a1d, as_, ad_);
  hipMemsetAsync(den, 0, (size_t)N_NODES * HEADS * 4, stream);
  k_edge<4><<<eb, 256, 0, stream>>>(ei, einv, ewc, den, as_, ad_);
  k_agg<4, true><<<N_NODES, 256, 0, stream>>>(hG, rowptr, csrS, ewc, den,
                                              b1, g1, be1, m1, v1, nullptr, hA);

  // ---- Layer 2: GATConv(1024 -> 4x256) + BN2 + ELU ----
  k_cvt<<<(C1 * (C1 / 2) + 255) / 256, 256, 0, stream>>>(W2, wh, C1, C1, C1);
  k_mfma_gemm<1><<<dim3(C1 / 128, M_PAD / 128), 256, 0, stream>>>(
      hA, wh, nullptr, hG, N_NODES, C1, C1);
  k_alpha<4><<<N_NODES, 256, 0, stream>>>(hG, a2s, a2d, as_, ad_);
  hipMemsetAsync(den, 0, (size_t)N_NODES * HEADS * 4, stream);
  k_edge<4><<<eb, 256, 0, stream>>>(ei, einv, ewc, den, as_, ad_);
  k_agg<4, true><<<N_NODES, 256, 0, stream>>>(hG, rowptr, csrS, ewc, den,
                                              b2, g2, be2, m2, v2, nullptr, hA);

  // ---- Layer 3: GATConv(1024 -> 256, heads=1) + ELU ----
  k_cvt<<<(DH * (C1 / 2) + 255) / 256, 256, 0, stream>>>(W3, wh, DH, C1, C1);
  k_mfma_gemm<1><<<dim3(DH / 128, M_PAD / 128), 256, 0, stream>>>(
      hA, wh, nullptr, hG, N_NODES, DH, C1);
  k_alpha<1><<<N_NODES, 64, 0, stream>>>(hG, a3s, a3d, as_, ad_);
  hipMemsetAsync(den, 0, (size_t)N_NODES * 4, stream);
  k_edge<1><<<eb, 256, 0, stream>>>(ei, einv, ewc, den, as_, ad_);
  k_agg<1, false><<<N_NODES, 64, 0, stream>>>(hG, rowptr, csrS, ewc, den,
                                              b3, nullptr, nullptr, nullptr,
                                              nullptr, buf1, nullptr);

  // ---- Fused MLP head ----
  k_mlp<<<N_NODES / MLP_NPB, 256, 0, stream>>>(buf1, fc1W, fc1b, fc2W, fc2b,
                                               out);
}